// Round 3
// baseline (678.489 us; speedup 1.0000x reference)
//
#include <hip/hip_runtime.h>
#include <stdint.h>

typedef unsigned short u16;
typedef __attribute__((ext_vector_type(8))) short short8;   // 8 x bf16 (4 VGPRs)
typedef __attribute__((ext_vector_type(4))) float f32x4;
typedef __attribute__((ext_vector_type(4))) unsigned short u16x4;

#define DMODEL 1024
#define SEQ    2048
#define BATCH  4
#define NHEAD  16
#define DH     64
#define NTOK   (BATCH*SEQ)
#define BH     (BATCH*NHEAD)
#define EPS    1e-5f

__device__ __forceinline__ float bf2f(u16 u){
  union { unsigned int u; float f; } x; x.u = ((unsigned int)u)<<16; return x.f;
}
__device__ __forceinline__ u16 f2bf(float f){
  union { float f; unsigned int u; } x; x.f = f;
  unsigned int r = x.u + 0x7FFFu + ((x.u>>16)&1u);
  return (u16)(r>>16);
}
__device__ __forceinline__ void split8(const float* v, short8& hi, short8& lo){
  #pragma unroll
  for (int j=0;j<8;++j){
    u16 h = f2bf(v[j]);
    float r = v[j] - bf2f(h);
    hi[j] = (short)h;
    lo[j] = (short)f2bf(r);
  }
}

__device__ __forceinline__ void gload_lds16(const void* g, void* l){
  __builtin_amdgcn_global_load_lds((__attribute__((address_space(1))) unsigned int*)g,
                                   (__attribute__((address_space(3))) unsigned int*)l,
                                   16, 0, 0);
}

// swizzle key for 128B-row tiles (8 chunks of 16B per row)
__device__ __forceinline__ int swzkey(int row){ return (row&7) ^ ((row>>3)&7); }

// ---------------- weight fp32 -> bf16 convert ----------------
__global__ __launch_bounds__(256) void cvt_f32_bf16(const float* __restrict__ src,
                                                    u16* __restrict__ dst, int n){
  int i = (blockIdx.x*256 + threadIdx.x)*4;
  if (i < n){
    float4 v = *reinterpret_cast<const float4*>(src + i);
    u16x4 o; o.x = f2bf(v.x); o.y = f2bf(v.y); o.z = f2bf(v.z); o.w = f2bf(v.w);
    *reinterpret_cast<u16x4*>(dst + i) = o;
  }
}

// fp32 -> hi/lo bf16 split
__global__ __launch_bounds__(256) void cvt_split(const float* __restrict__ src,
                                                 u16* __restrict__ hi,
                                                 u16* __restrict__ lo, int n){
  int i = (blockIdx.x*256 + threadIdx.x)*4;
  if (i < n){
    float4 v = *reinterpret_cast<const float4*>(src + i);
    float vv[4] = {v.x, v.y, v.z, v.w};
    u16x4 oh, ol;
    #pragma unroll
    for (int j=0;j<4;++j){
      u16 h = f2bf(vv[j]);
      oh[j] = h;
      ol[j] = f2bf(vv[j] - bf2f(h));
    }
    *reinterpret_cast<u16x4*>(hi + i) = oh;
    *reinterpret_cast<u16x4*>(lo + i) = ol;
  }
}

// ---------------- LayerNorm ----------------
__global__ __launch_bounds__(256) void ln_kernel(const float* __restrict__ in0,
                                                 const float* __restrict__ in1,
                                                 const float* __restrict__ sc,
                                                 const float* __restrict__ bi,
                                                 float* __restrict__ of32,
                                                 u16* __restrict__ obf){
  int row = blockIdx.x;
  int t = threadIdx.x;
  size_t base = (size_t)row*DMODEL + t*4;
  float4 v = *reinterpret_cast<const float4*>(in0 + base);
  if (in1){
    float4 a = *reinterpret_cast<const float4*>(in1 + base);
    v.x += a.x; v.y += a.y; v.z += a.z; v.w += a.w;
  }
  float s  = v.x+v.y+v.z+v.w;
  float ss = v.x*v.x+v.y*v.y+v.z*v.z+v.w*v.w;
  #pragma unroll
  for (int m=1;m<64;m<<=1){ s += __shfl_xor(s,m); ss += __shfl_xor(ss,m); }
  __shared__ float rs_[4], rss_[4];
  int w = t>>6, l = t&63;
  if (l==0){ rs_[w]=s; rss_[w]=ss; }
  __syncthreads();
  s  = rs_[0]+rs_[1]+rs_[2]+rs_[3];
  ss = rss_[0]+rss_[1]+rss_[2]+rss_[3];
  float mu  = s * (1.0f/DMODEL);
  float var = ss * (1.0f/DMODEL) - mu*mu;
  var = fmaxf(var, 0.0f);
  float r = rsqrtf(var + EPS);
  float4 g = *reinterpret_cast<const float4*>(sc + t*4);
  float4 b = *reinterpret_cast<const float4*>(bi + t*4);
  float o0 = (v.x-mu)*r*g.x + b.x;
  float o1 = (v.y-mu)*r*g.y + b.y;
  float o2 = (v.z-mu)*r*g.z + b.z;
  float o3 = (v.w-mu)*r*g.w + b.w;
  if (of32){
    float4 ov; ov.x=o0; ov.y=o1; ov.z=o2; ov.w=o3;
    *reinterpret_cast<float4*>(of32 + base) = ov;
  }
  if (obf){
    u16x4 ob; ob.x=f2bf(o0); ob.y=f2bf(o1); ob.z=f2bf(o2); ob.w=f2bf(o3);
    *reinterpret_cast<u16x4*>(obf + base) = ob;
  }
}

// ---------------- split-precision QKV GEMM ----------------
// C = A[M][K]_f32 @ W[3072][K]^T (hi/lo split, 3 MFMAs), writes head-major
// qh/ql/kh/kl (hi/lo bf16) and v (bf16).
__global__ __launch_bounds__(256) void gemm_qkv_split(const float* __restrict__ A,
                                                      const u16* __restrict__ whi,
                                                      const u16* __restrict__ wlo,
                                                      u16* __restrict__ qh, u16* __restrict__ ql,
                                                      u16* __restrict__ kh, u16* __restrict__ kl,
                                                      u16* __restrict__ vbf){
  const int K = DMODEL;
  __shared__ u16 Ah[128*32], Al[128*32], Bh[128*32], Bl[128*32];
  int t = threadIdx.x, l = t&63, w = t>>6;
  int bm = blockIdx.y, bn = blockIdx.x;
  int wr = w>>1, wc = w&1;

  f32x4 acc[4][4];
  #pragma unroll
  for (int m=0;m<4;++m)
    #pragma unroll
    for (int n=0;n<4;++n)
      #pragma unroll
      for (int i=0;i<4;++i) acc[m][n][i] = 0.0f;

  int r = t>>1, half = t&1;
  const int nk = K/32;
  for (int kt=0; kt<nk; ++kt){
    int k0 = kt*32;
    __syncthreads();
    // stage A hi/lo (reg-split from f32)
    {
      const float* p = A + (size_t)(bm*128 + r)*K + k0 + half*16;
      float buf[16];
      #pragma unroll
      for (int q=0;q<4;++q)
        *reinterpret_cast<float4*>(&buf[q*4]) = reinterpret_cast<const float4*>(p)[q];
      #pragma unroll
      for (int j=0;j<2;++j){
        short8 hi, lo; split8(&buf[j*8], hi, lo);
        int pc = (half*2+j) ^ (r&3);
        *reinterpret_cast<short8*>(&Ah[r*32 + pc*8]) = hi;
        *reinterpret_cast<short8*>(&Al[r*32 + pc*8]) = lo;
      }
    }
    // stage W hi/lo via global_load_lds (pre-swizzled source)
    #pragma unroll
    for (int i=0;i<2;++i){
      int slot = i*256 + t;
      int row = slot>>2, pc = slot&3;
      int lc = pc ^ (row&3);
      gload_lds16(whi + (size_t)(bn*128 + row)*K + k0 + lc*8, &Bh[slot*8]);
      gload_lds16(wlo + (size_t)(bn*128 + row)*K + k0 + lc*8, &Bl[slot*8]);
    }
    __syncthreads();
    short8 ah[4], al[4], bh[4], bl[4];
    #pragma unroll
    for (int m=0;m<4;++m){
      int row = wr*64 + m*16 + (l&15);
      int cp = (l>>4) ^ (row&3);
      ah[m] = *reinterpret_cast<const short8*>(&Ah[row*32 + cp*8]);
      al[m] = *reinterpret_cast<const short8*>(&Al[row*32 + cp*8]);
    }
    #pragma unroll
    for (int n=0;n<4;++n){
      int row = wc*64 + n*16 + (l&15);
      int cp = (l>>4) ^ (row&3);
      bh[n] = *reinterpret_cast<const short8*>(&Bh[row*32 + cp*8]);
      bl[n] = *reinterpret_cast<const short8*>(&Bl[row*32 + cp*8]);
    }
    #pragma unroll
    for (int m=0;m<4;++m)
      #pragma unroll
      for (int n=0;n<4;++n){
        acc[m][n] = __builtin_amdgcn_mfma_f32_16x16x32_bf16(ah[m], bh[n], acc[m][n], 0,0,0);
        acc[m][n] = __builtin_amdgcn_mfma_f32_16x16x32_bf16(ah[m], bl[n], acc[m][n], 0,0,0);
        acc[m][n] = __builtin_amdgcn_mfma_f32_16x16x32_bf16(al[m], bh[n], acc[m][n], 0,0,0);
      }
  }

  // epilogue: head-major hi/lo writes. sel uniform per bn.
  #pragma unroll
  for (int m=0;m<4;++m){
    int row0 = bm*128 + wr*64 + m*16 + ((l>>4)<<2);
    #pragma unroll
    for (int n=0;n<4;++n){
      int col = bn*128 + wc*64 + n*16 + (l&15);
      int dg = col & 1023;
      int hh = dg >> 6, dh = dg & 63;
      #pragma unroll
      for (int i=0;i<4;++i){
        int token = row0 + i;
        int bb = token >> 11, s = token & 2047;
        size_t off = ((size_t)(bb*NHEAD + hh)*SEQ + s)*DH + dh;
        float vv = acc[m][n][i];
        if (bn < 8){
          u16 hi16 = f2bf(vv);
          qh[off] = hi16; ql[off] = f2bf(vv - bf2f(hi16));
        } else if (bn < 16){
          u16 hi16 = f2bf(vv);
          kh[off] = hi16; kl[off] = f2bf(vv - bf2f(hi16));
        } else {
          vbf[off] = f2bf(vv);
        }
      }
    }
  }
}

// ---------------- V transpose: [bh][s][64] -> [bh][64][s] ----------------
__global__ __launch_bounds__(256) void vtrans_kernel(const u16* __restrict__ v,
                                                     u16* __restrict__ vT){
  __shared__ u16 tile[64*72];
  int id = blockIdx.x;
  int bh = id>>5, tc = id&31;
  int t = threadIdx.x;
  const u16* src = v + ((size_t)bh*SEQ + tc*64)*DH;
  #pragma unroll
  for (int i=0;i<2;++i){
    int slot = i*256+t; int row = slot>>3, c = slot&7;
    *reinterpret_cast<short8*>(&tile[row*72 + c*8]) =
        *reinterpret_cast<const short8*>(src + row*64 + c*8);
  }
  __syncthreads();
  u16* dst = vT + (size_t)bh*DH*SEQ;
  #pragma unroll
  for (int i=0;i<2;++i){
    int oslot = i*256+t; int d = oslot>>3, tch = oslot&7;
    short8 o;
    #pragma unroll
    for (int j=0;j<8;++j) o[j] = (short)tile[(tch*8+j)*72 + d];
    *reinterpret_cast<short8*>(dst + (size_t)d*SEQ + tc*64 + tch*8) = o;
  }
}

// ---------------- bf16 GEMM (FFN) ----------------
template<bool BIAS, bool RELU, bool RES, bool OUTF32>
__global__ __launch_bounds__(256) void gemm_bt(const u16* __restrict__ A,
                                               const u16* __restrict__ W,
                                               const float* __restrict__ bias,
                                               const float* __restrict__ resid,
                                               void* __restrict__ outp,
                                               int M, int N, int K){
  __shared__ u16 As[128*32];
  __shared__ u16 Bs[128*32];
  int t = threadIdx.x, l = t&63, w = t>>6;
  int bm = blockIdx.y, bn = blockIdx.x;
  int wr = w>>1, wc = w&1;
  f32x4 acc[4][4];
  #pragma unroll
  for (int m=0;m<4;++m)
    #pragma unroll
    for (int n=0;n<4;++n)
      #pragma unroll
      for (int i=0;i<4;++i) acc[m][n][i] = 0.0f;

  const int nk = K/32;
  for (int kt=0; kt<nk; ++kt){
    int k0 = kt*32;
    __syncthreads();
    #pragma unroll
    for (int i=0;i<2;++i){
      int idx = i*256 + t;
      int r = idx>>2;
      int cc = (idx&3) ^ (r&3);
      gload_lds16(A + (size_t)(bm*128 + r)*K + k0 + cc*8, &As[idx*8]);
      gload_lds16(W + (size_t)(bn*128 + r)*K + k0 + cc*8, &Bs[idx*8]);
    }
    __syncthreads();
    short8 af[4], bf[4];
    #pragma unroll
    for (int m=0;m<4;++m){
      int row = wr*64 + m*16 + (l&15);
      int cp = (l>>4) ^ (row&3);
      af[m] = *reinterpret_cast<const short8*>(&As[row*32 + cp*8]);
    }
    #pragma unroll
    for (int n=0;n<4;++n){
      int row = wc*64 + n*16 + (l&15);
      int cp = (l>>4) ^ (row&3);
      bf[n] = *reinterpret_cast<const short8*>(&Bs[row*32 + cp*8]);
    }
    #pragma unroll
    for (int m=0;m<4;++m)
      #pragma unroll
      for (int n=0;n<4;++n)
        acc[m][n] = __builtin_amdgcn_mfma_f32_16x16x32_bf16(af[m], bf[n], acc[m][n], 0,0,0);
  }

  #pragma unroll
  for (int m=0;m<4;++m){
    int row0 = bm*128 + wr*64 + m*16 + ((l>>4)<<2);
    #pragma unroll
    for (int n=0;n<4;++n){
      int col = bn*128 + wc*64 + n*16 + (l&15);
      float bv = BIAS ? bias[col] : 0.0f;
      #pragma unroll
      for (int i=0;i<4;++i){
        float vv = acc[m][n][i] + bv;
        if (RELU) vv = fmaxf(vv, 0.0f);
        size_t off = (size_t)(row0+i)*N + col;
        if (RES) vv += resid[off];
        if (OUTF32) ((float*)outp)[off] = vv;
        else        ((u16*)outp)[off] = f2bf(vv);
      }
    }
  }
}

// ---------------- flash attention v2 ----------------
// QBLK=128, 4 waves x 32 q-rows; KBLK=64; double-buffered gload_lds staging.
#define QBLK 128
#define KBLK 64

__global__ __launch_bounds__(256) void attn_kernel(const u16* __restrict__ qh,
                                                   const u16* __restrict__ ql,
                                                   const u16* __restrict__ kh,
                                                   const u16* __restrict__ kl,
                                                   const u16* __restrict__ vT,
                                                   float* __restrict__ att){
  int id = blockIdx.x;                      // XCD-aware decode: same bh -> same XCD
  int bh = (id & 7) + ((id >> 7) << 3);
  int qb = (id >> 3) & 15;
  int t = threadIdx.x, l = t&63, w = t>>6;

  const size_t hbase = (size_t)bh * SEQ * DH;
  const u16* khb = kh + hbase;
  const u16* klb = kl + hbase;
  const u16* vtb = vT + hbase;              // [64][SEQ]
  int q0 = qb*QBLK + w*32;

  // Q fragments (2 qsubs x 2 k-chunks), hi+lo
  short8 qfh[2][2], qfl[2][2];
  #pragma unroll
  for (int qs=0;qs<2;++qs)
    #pragma unroll
    for (int kc=0;kc<2;++kc){
      size_t off = hbase + (size_t)(q0 + qs*16 + (l&15))*DH + kc*32 + ((l>>4)<<3);
      qfh[qs][kc] = *reinterpret_cast<const short8*>(qh + off);
      qfl[qs][kc] = *reinterpret_cast<const short8*>(ql + off);
    }

  __shared__ u16 Kh2[2][KBLK*64];
  __shared__ u16 Kl2[2][KBLK*64];
  __shared__ u16 Vt2[2][KBLK*64];
  __shared__ u16 Pl[4][32*64];
  char* PlB = (char*)&Pl[w][0];

  f32x4 o[2][4];
  #pragma unroll
  for (int qs=0;qs<2;++qs)
    #pragma unroll
    for (int d=0;d<4;++d)
      #pragma unroll
      for (int i=0;i<4;++i) o[qs][d][i] = 0.0f;
  float m_run[2][4], l_run[2][4];
  #pragma unroll
  for (int qs=0;qs<2;++qs)
    #pragma unroll
    for (int i=0;i<4;++i){ m_run[qs][i] = -3.0e38f; l_run[qs][i] = 0.0f; }

  // stage tile kt into buffer bb (pre-swizzled source -> linear LDS dest)
  #define STAGE(bb, kt)                                                         \
    { _Pragma("unroll")                                                         \
      for (int i_=0;i_<2;++i_){                                                 \
        int slot = i_*256 + t;                                                  \
        int row = slot>>3, pc = slot&7;                                         \
        int lc = pc ^ swzkey(row);                                              \
        gload_lds16(khb + ((size_t)((kt)*KBLK + row))*DH + lc*8, &Kh2[bb][slot*8]); \
        gload_lds16(klb + ((size_t)((kt)*KBLK + row))*DH + lc*8, &Kl2[bb][slot*8]); \
        gload_lds16(vtb + (size_t)row*SEQ + (kt)*KBLK + lc*8,    &Vt2[bb][slot*8]); \
      } }

  STAGE(0, 0);
  int cur = 0;
  const int NT = SEQ/KBLK;
  for (int kt=0; kt<NT; ++kt){
    __syncthreads();                 // compiler emits vmcnt(0) drain before barrier
    if (kt+1 < NT) STAGE(cur^1, kt+1);

    char* KhB = (char*)&Kh2[cur][0];
    char* KlB = (char*)&Kl2[cur][0];
    char* VtB = (char*)&Vt2[cur][0];

    // ---- QK^T (split, 3 MFMAs per chunk) ----
    f32x4 sc[2][4];
    #pragma unroll
    for (int qs=0;qs<2;++qs)
      #pragma unroll
      for (int st=0;st<4;++st)
        #pragma unroll
        for (int i=0;i<4;++i) sc[qs][st][i] = 0.0f;

    #pragma unroll
    for (int kc=0;kc<2;++kc)
      #pragma unroll
      for (int st=0;st<4;++st){
        int rr = st*16 + (l&15);
        int pcK = (kc*4 + (l>>4)) ^ swzkey(rr);
        short8 kfh = *reinterpret_cast<const short8*>(KhB + rr*128 + pcK*16);
        short8 kfl = *reinterpret_cast<const short8*>(KlB + rr*128 + pcK*16);
        #pragma unroll
        for (int qs=0;qs<2;++qs){
          sc[qs][st] = __builtin_amdgcn_mfma_f32_16x16x32_bf16(qfh[qs][kc], kfh, sc[qs][st], 0,0,0);
          sc[qs][st] = __builtin_amdgcn_mfma_f32_16x16x32_bf16(qfh[qs][kc], kfl, sc[qs][st], 0,0,0);
          sc[qs][st] = __builtin_amdgcn_mfma_f32_16x16x32_bf16(qfl[qs][kc], kfh, sc[qs][st], 0,0,0);
        }
      }

    // ---- online softmax + P write (per qsub) ----
    #pragma unroll
    for (int qs=0;qs<2;++qs){
      float mt[4];
      #pragma unroll
      for (int i=0;i<4;++i)
        mt[i] = fmaxf(fmaxf(sc[qs][0][i], sc[qs][1][i]), fmaxf(sc[qs][2][i], sc[qs][3][i]));
      #pragma unroll
      for (int mk=1; mk<16; mk<<=1)
        #pragma unroll
        for (int i=0;i<4;++i) mt[i] = fmaxf(mt[i], __shfl_xor(mt[i], mk));

      float scl[4], rsum[4];
      u16 pb[4][4];
      #pragma unroll
      for (int i=0;i<4;++i){
        float mn = fmaxf(m_run[qs][i], mt[i]);
        scl[i] = __expf(m_run[qs][i] - mn);
        m_run[qs][i] = mn;
        float sum = 0.0f;
        #pragma unroll
        for (int st=0;st<4;++st){
          float p = __expf(sc[qs][st][i] - mn);
          sum += p;
          pb[st][i] = f2bf(p);
        }
        rsum[i] = sum;
      }
      #pragma unroll
      for (int mk=1; mk<16; mk<<=1)
        #pragma unroll
        for (int i=0;i<4;++i) rsum[i] += __shfl_xor(rsum[i], mk);
      #pragma unroll
      for (int i=0;i<4;++i) l_run[qs][i] = l_run[qs][i]*scl[i] + rsum[i];
      #pragma unroll
      for (int d=0;d<4;++d)
        #pragma unroll
        for (int i=0;i<4;++i) o[qs][d][i] *= scl[i];

      // P write (swizzled)
      #pragma unroll
      for (int i=0;i<4;++i){
        int pr = qs*16 + ((l>>4)<<2) + i;
        int sw = swzkey(pr) << 4;
        #pragma unroll
        for (int st=0;st<4;++st){
          int col = st*16 + (l&15);
          *reinterpret_cast<u16*>(PlB + pr*128 + (((col>>3)<<4) ^ sw) + ((col&7)<<1)) = pb[st][i];
        }
      }
    }

    // wave-internal drain: P writes visible before P reads
    asm volatile("s_waitcnt lgkmcnt(0)" ::: "memory");
    __builtin_amdgcn_sched_barrier(0);

    // ---- PV ----
    #pragma unroll
    for (int kc=0;kc<2;++kc){
      short8 pa[2];
      #pragma unroll
      for (int qs=0;qs<2;++qs){
        int pr = qs*16 + (l&15);
        int pcP = (kc*4 + (l>>4)) ^ swzkey(pr);
        pa[qs] = *reinterpret_cast<const short8*>(PlB + pr*128 + pcP*16);
      }
      #pragma unroll
      for (int d=0;d<4;++d){
        int vr = d*16 + (l&15);
        int pcV = (kc*4 + (l>>4)) ^ swzkey(vr);
        short8 vf = *reinterpret_cast<const short8*>(VtB + vr*128 + pcV*16);
        o[0][d] = __builtin_amdgcn_mfma_f32_16x16x32_bf16(pa[0], vf, o[0][d], 0,0,0);
        o[1][d] = __builtin_amdgcn_mfma_f32_16x16x32_bf16(pa[1], vf, o[1][d], 0,0,0);
      }
    }
    cur ^= 1;
  }

  // epilogue
  int b = bh >> 4, hhd = bh & 15;
  #pragma unroll
  for (int qs=0;qs<2;++qs)
    #pragma unroll
    for (int i=0;i<4;++i){
      float inv = 1.0f / l_run[qs][i];
      int token = b*SEQ + q0 + qs*16 + ((l>>4)<<2) + i;
      #pragma unroll
      for (int d=0;d<4;++d)
        att[(size_t)token*DMODEL + hhd*DH + d*16 + (l&15)] = o[qs][d][i] * inv;
    }
}

// ---------------- launch ----------------
extern "C" void kernel_launch(void* const* d_in, const int* in_sizes, int n_in,
                              void* d_out, int out_size, void* d_ws, size_t ws_size,
                              hipStream_t stream){
  (void)in_sizes; (void)n_in; (void)out_size; (void)ws_size;
  const float* x    = (const float*)d_in[0];
  const float* Wq   = (const float*)d_in[1];
  const float* Wk   = (const float*)d_in[2];
  const float* Wv   = (const float*)d_in[3];
  const float* W1   = (const float*)d_in[4];
  const float* b1   = (const float*)d_in[5];
  const float* W2   = (const float*)d_in[6];
  const float* b2   = (const float*)d_in[7];
  const float* ln1s = (const float*)d_in[8];
  const float* ln1b = (const float*)d_in[9];
  const float* ln2s = (const float*)d_in[10];
  const float* ln2b = (const float*)d_in[11];

  char* ws = (char*)d_ws;
  float* xn_f32  = (float*)ws;  ws += (size_t)NTOK*DMODEL*4;
  float* att_f32 = (float*)ws;  ws += (size_t)NTOK*DMODEL*4;
  float* xt_f32  = (float*)ws;  ws += (size_t)NTOK*DMODEL*4;
  u16* xt_bf     = (u16*)ws;    ws += (size_t)NTOK*DMODEL*2;
  u16* vbf       = (u16*)ws;    ws += (size_t)NTOK*DMODEL*2;   // aliased: h_bf later
  u16* h_bf      = vbf;
  u16* vT        = (u16*)ws;    ws += (size_t)NTOK*DMODEL*2;
  u16* qh        = (u16*)ws;    ws += (size_t)NTOK*DMODEL*2;
  u16* ql        = (u16*)ws;    ws += (size_t)NTOK*DMODEL*2;
  u16* kh        = (u16*)ws;    ws += (size_t)NTOK*DMODEL*2;
  u16* kl        = (u16*)ws;    ws += (size_t)NTOK*DMODEL*2;
  u16* whi       = (u16*)ws;    ws += (size_t)3*DMODEL*DMODEL*2;
  u16* wlo       = (u16*)ws;    ws += (size_t)3*DMODEL*DMODEL*2;
  u16* w1_bf     = (u16*)ws;    ws += (size_t)DMODEL*DMODEL*2;
  u16* w2_bf     = (u16*)ws;    ws += (size_t)DMODEL*DMODEL*2;

  const int nW = DMODEL*DMODEL;
  const int cvtBlocks = nW/4/256;
  cvt_split<<<cvtBlocks, 256, 0, stream>>>(Wq, whi,        wlo,        nW);
  cvt_split<<<cvtBlocks, 256, 0, stream>>>(Wk, whi + nW,   wlo + nW,   nW);
  cvt_split<<<cvtBlocks, 256, 0, stream>>>(Wv, whi + 2*nW, wlo + 2*nW, nW);
  cvt_f32_bf16<<<cvtBlocks, 256, 0, stream>>>(W1, w1_bf, nW);
  cvt_f32_bf16<<<cvtBlocks, 256, 0, stream>>>(W2, w2_bf, nW);

  ln_kernel<<<NTOK, 256, 0, stream>>>(x, nullptr, ln1s, ln1b, xn_f32, nullptr);

  gemm_qkv_split<<<dim3(3*DMODEL/128, NTOK/128), 256, 0, stream>>>(
      xn_f32, whi, wlo, qh, ql, kh, kl, vbf);

  vtrans_kernel<<<BH*(SEQ/64), 256, 0, stream>>>(vbf, vT);

  attn_kernel<<<BH*(SEQ/QBLK), 256, 0, stream>>>(qh, ql, kh, kl, vT, att_f32);

  ln_kernel<<<NTOK, 256, 0, stream>>>(xn_f32, att_f32, ln2s, ln2b, xt_f32, xt_bf);

  gemm_bt<true,true,false,false><<<dim3(DMODEL/128, NTOK/128), 256, 0, stream>>>(
      xt_bf, w1_bf, b1, nullptr, h_bf, NTOK, DMODEL, DMODEL);

  gemm_bt<true,false,true,true><<<dim3(DMODEL/128, NTOK/128), 256, 0, stream>>>(
      h_bf, w2_bf, b2, xt_f32, d_out, NTOK, DMODEL, DMODEL);
}

// Round 4
// 459.918 us; speedup vs baseline: 1.4752x; 1.4752x over previous
//
#include <hip/hip_runtime.h>
#include <stdint.h>

typedef unsigned short u16;
typedef __attribute__((ext_vector_type(8))) short short8;   // 8 x bf16 (4 VGPRs)
typedef __attribute__((ext_vector_type(4))) float f32x4;
typedef __attribute__((ext_vector_type(4))) unsigned short u16x4;

#define DMODEL 1024
#define SEQ    2048
#define BATCH  4
#define NHEAD  16
#define DH     64
#define NTOK   (BATCH*SEQ)
#define BH     (BATCH*NHEAD)
#define EPS    1e-5f

__device__ __forceinline__ float bf2f(u16 u){
  union { unsigned int u; float f; } x; x.u = ((unsigned int)u)<<16; return x.f;
}
__device__ __forceinline__ u16 f2bf(float f){
  union { float f; unsigned int u; } x; x.f = f;
  unsigned int r = x.u + 0x7FFFu + ((x.u>>16)&1u);
  return (u16)(r>>16);
}

__device__ __forceinline__ void gload_lds16(const void* g, void* l){
  __builtin_amdgcn_global_load_lds((__attribute__((address_space(1))) unsigned int*)g,
                                   (__attribute__((address_space(3))) unsigned int*)l,
                                   16, 0, 0);
}

// swizzle key for 128B-row tiles (8 chunks of 16B per row)
__device__ __forceinline__ int swzkey(int row){ return (row&7) ^ ((row>>3)&7); }

// ---------------- weight fp32 -> bf16 convert ----------------
__global__ __launch_bounds__(256) void cvt_f32_bf16(const float* __restrict__ src,
                                                    u16* __restrict__ dst, int n){
  int i = (blockIdx.x*256 + threadIdx.x)*4;
  if (i < n){
    float4 v = *reinterpret_cast<const float4*>(src + i);
    u16x4 o; o.x = f2bf(v.x); o.y = f2bf(v.y); o.z = f2bf(v.z); o.w = f2bf(v.w);
    *reinterpret_cast<u16x4*>(dst + i) = o;
  }
}

// fp32 -> hi/lo bf16 split
__global__ __launch_bounds__(256) void cvt_split(const float* __restrict__ src,
                                                 u16* __restrict__ hi,
                                                 u16* __restrict__ lo, int n){
  int i = (blockIdx.x*256 + threadIdx.x)*4;
  if (i < n){
    float4 v = *reinterpret_cast<const float4*>(src + i);
    float vv[4] = {v.x, v.y, v.z, v.w};
    u16x4 oh, ol;
    #pragma unroll
    for (int j=0;j<4;++j){
      u16 h = f2bf(vv[j]);
      oh[j] = h;
      ol[j] = f2bf(vv[j] - bf2f(h));
    }
    *reinterpret_cast<u16x4*>(hi + i) = oh;
    *reinterpret_cast<u16x4*>(lo + i) = ol;
  }
}

// ---------------- LayerNorm: writes f32 (opt) + bf16 hi (opt) + bf16 lo (opt) ----------------
__global__ __launch_bounds__(256) void ln_kernel(const float* __restrict__ in0,
                                                 const float* __restrict__ in1,
                                                 const float* __restrict__ sc,
                                                 const float* __restrict__ bi,
                                                 float* __restrict__ of32,
                                                 u16* __restrict__ ohi,
                                                 u16* __restrict__ olo){
  int row = blockIdx.x;
  int t = threadIdx.x;
  size_t base = (size_t)row*DMODEL + t*4;
  float4 v = *reinterpret_cast<const float4*>(in0 + base);
  if (in1){
    float4 a = *reinterpret_cast<const float4*>(in1 + base);
    v.x += a.x; v.y += a.y; v.z += a.z; v.w += a.w;
  }
  float s  = v.x+v.y+v.z+v.w;
  float ss = v.x*v.x+v.y*v.y+v.z*v.z+v.w*v.w;
  #pragma unroll
  for (int m=1;m<64;m<<=1){ s += __shfl_xor(s,m); ss += __shfl_xor(ss,m); }
  __shared__ float rs_[4], rss_[4];
  int w = t>>6, l = t&63;
  if (l==0){ rs_[w]=s; rss_[w]=ss; }
  __syncthreads();
  s  = rs_[0]+rs_[1]+rs_[2]+rs_[3];
  ss = rss_[0]+rss_[1]+rss_[2]+rss_[3];
  float mu  = s * (1.0f/DMODEL);
  float var = ss * (1.0f/DMODEL) - mu*mu;
  var = fmaxf(var, 0.0f);
  float r = rsqrtf(var + EPS);
  float4 g = *reinterpret_cast<const float4*>(sc + t*4);
  float4 b = *reinterpret_cast<const float4*>(bi + t*4);
  float o0 = (v.x-mu)*r*g.x + b.x;
  float o1 = (v.y-mu)*r*g.y + b.y;
  float o2 = (v.z-mu)*r*g.z + b.z;
  float o3 = (v.w-mu)*r*g.w + b.w;
  if (of32){
    float4 ov; ov.x=o0; ov.y=o1; ov.z=o2; ov.w=o3;
    *reinterpret_cast<float4*>(of32 + base) = ov;
  }
  float oo[4] = {o0,o1,o2,o3};
  if (ohi){
    u16x4 ob;
    #pragma unroll
    for (int j=0;j<4;++j) ob[j] = f2bf(oo[j]);
    *reinterpret_cast<u16x4*>(ohi + base) = ob;
    if (olo){
      u16x4 obl;
      #pragma unroll
      for (int j=0;j<4;++j) obl[j] = f2bf(oo[j] - bf2f(ob[j]));
      *reinterpret_cast<u16x4*>(olo + base) = obl;
    }
  }
}

// ---------------- split-precision Q,K GEMM ----------------
// C = A @ W^T for W = [Wq; Wk] (N=2048), hi/lo split (3 MFMAs). All staging
// via global_load_lds with both-sides chunk swizzle. Writes head-major hi/lo.
__global__ __launch_bounds__(256) void gemm_qk_split(const u16* __restrict__ xnh,
                                                     const u16* __restrict__ xnl,
                                                     const u16* __restrict__ whi,
                                                     const u16* __restrict__ wlo,
                                                     u16* __restrict__ qh, u16* __restrict__ ql,
                                                     u16* __restrict__ kh, u16* __restrict__ kl){
  const int K = DMODEL;
  __shared__ u16 Ah[128*32], Al[128*32], Bh[128*32], Bl[128*32];
  int t = threadIdx.x, l = t&63, w = t>>6;
  int bm = blockIdx.y, bn = blockIdx.x;
  int wr = w>>1, wc = w&1;

  f32x4 acc[4][4];
  #pragma unroll
  for (int m=0;m<4;++m)
    #pragma unroll
    for (int n=0;n<4;++n)
      #pragma unroll
      for (int i=0;i<4;++i) acc[m][n][i] = 0.0f;

  const int nk = K/32;
  for (int kt=0; kt<nk; ++kt){
    int k0 = kt*32;
    __syncthreads();
    #pragma unroll
    for (int i=0;i<2;++i){
      int slot = i*256 + t;
      int row = slot>>2, pc = slot&3;
      int lc = pc ^ (row&3);
      gload_lds16(xnh + (size_t)(bm*128 + row)*K + k0 + lc*8, &Ah[slot*8]);
      gload_lds16(xnl + (size_t)(bm*128 + row)*K + k0 + lc*8, &Al[slot*8]);
      gload_lds16(whi + (size_t)(bn*128 + row)*K + k0 + lc*8, &Bh[slot*8]);
      gload_lds16(wlo + (size_t)(bn*128 + row)*K + k0 + lc*8, &Bl[slot*8]);
    }
    __syncthreads();
    short8 ah[4], al[4], bh[4], bl[4];
    #pragma unroll
    for (int m=0;m<4;++m){
      int row = wr*64 + m*16 + (l&15);
      int cp = (l>>4) ^ (row&3);
      ah[m] = *reinterpret_cast<const short8*>(&Ah[row*32 + cp*8]);
      al[m] = *reinterpret_cast<const short8*>(&Al[row*32 + cp*8]);
    }
    #pragma unroll
    for (int n=0;n<4;++n){
      int row = wc*64 + n*16 + (l&15);
      int cp = (l>>4) ^ (row&3);
      bh[n] = *reinterpret_cast<const short8*>(&Bh[row*32 + cp*8]);
      bl[n] = *reinterpret_cast<const short8*>(&Bl[row*32 + cp*8]);
    }
    __builtin_amdgcn_s_setprio(1);
    #pragma unroll
    for (int m=0;m<4;++m)
      #pragma unroll
      for (int n=0;n<4;++n){
        acc[m][n] = __builtin_amdgcn_mfma_f32_16x16x32_bf16(ah[m], bh[n], acc[m][n], 0,0,0);
        acc[m][n] = __builtin_amdgcn_mfma_f32_16x16x32_bf16(ah[m], bl[n], acc[m][n], 0,0,0);
        acc[m][n] = __builtin_amdgcn_mfma_f32_16x16x32_bf16(al[m], bh[n], acc[m][n], 0,0,0);
      }
    __builtin_amdgcn_s_setprio(0);
  }

  // epilogue: head-major hi/lo writes (bn<8 -> Q, else K)
  #pragma unroll
  for (int m=0;m<4;++m){
    int row0 = bm*128 + wr*64 + m*16 + ((l>>4)<<2);
    #pragma unroll
    for (int n=0;n<4;++n){
      int col = bn*128 + wc*64 + n*16 + (l&15);
      int dg = col & 1023;
      int hh = dg >> 6, dh = dg & 63;
      #pragma unroll
      for (int i=0;i<4;++i){
        int token = row0 + i;
        int bb = token >> 11, s = token & 2047;
        size_t off = ((size_t)(bb*NHEAD + hh)*SEQ + s)*DH + dh;
        float vv = acc[m][n][i];
        u16 hi16 = f2bf(vv);
        u16 lo16 = f2bf(vv - bf2f(hi16));
        if (col < 1024){ qh[off] = hi16; ql[off] = lo16; }
        else           { kh[off] = hi16; kl[off] = lo16; }
      }
    }
  }
}

// ---------------- V transpose: row-major [token][1024] -> vT[bh][64][SEQ] ----------------
__global__ __launch_bounds__(256) void vtrans_kernel(const u16* __restrict__ vrow,
                                                     u16* __restrict__ vT){
  __shared__ u16 tile[64*72];
  int id = blockIdx.x;
  int bh = id>>5, tc = id&31;
  int b = bh >> 4, h = bh & 15;
  int t = threadIdx.x;
  const u16* src = vrow + ((size_t)(b*SEQ) + tc*64)*DMODEL + h*DH;
  #pragma unroll
  for (int i=0;i<2;++i){
    int slot = i*256+t; int row = slot>>3, c = slot&7;
    *reinterpret_cast<short8*>(&tile[row*72 + c*8]) =
        *reinterpret_cast<const short8*>(src + (size_t)row*DMODEL + c*8);
  }
  __syncthreads();
  u16* dst = vT + (size_t)bh*DH*SEQ;
  #pragma unroll
  for (int i=0;i<2;++i){
    int oslot = i*256+t; int d = oslot>>3, tch = oslot&7;
    short8 o;
    #pragma unroll
    for (int j=0;j<8;++j) o[j] = (short)tile[(tch*8+j)*72 + d];
    *reinterpret_cast<short8*>(dst + (size_t)d*SEQ + tc*64 + tch*8) = o;
  }
}

// ---------------- bf16 GEMM (V projection + FFN) ----------------
template<bool BIAS, bool RELU, bool RES, bool OUTF32>
__global__ __launch_bounds__(256) void gemm_bt(const u16* __restrict__ A,
                                               const u16* __restrict__ W,
                                               const float* __restrict__ bias,
                                               const float* __restrict__ resid,
                                               void* __restrict__ outp,
                                               int M, int N, int K){
  __shared__ u16 As[128*32];
  __shared__ u16 Bs[128*32];
  int t = threadIdx.x, l = t&63, w = t>>6;
  int bm = blockIdx.y, bn = blockIdx.x;
  int wr = w>>1, wc = w&1;
  f32x4 acc[4][4];
  #pragma unroll
  for (int m=0;m<4;++m)
    #pragma unroll
    for (int n=0;n<4;++n)
      #pragma unroll
      for (int i=0;i<4;++i) acc[m][n][i] = 0.0f;

  const int nk = K/32;
  for (int kt=0; kt<nk; ++kt){
    int k0 = kt*32;
    __syncthreads();
    #pragma unroll
    for (int i=0;i<2;++i){
      int idx = i*256 + t;
      int r = idx>>2;
      int cc = (idx&3) ^ (r&3);
      gload_lds16(A + (size_t)(bm*128 + r)*K + k0 + cc*8, &As[idx*8]);
      gload_lds16(W + (size_t)(bn*128 + r)*K + k0 + cc*8, &Bs[idx*8]);
    }
    __syncthreads();
    short8 af[4], bf[4];
    #pragma unroll
    for (int m=0;m<4;++m){
      int row = wr*64 + m*16 + (l&15);
      int cp = (l>>4) ^ (row&3);
      af[m] = *reinterpret_cast<const short8*>(&As[row*32 + cp*8]);
    }
    #pragma unroll
    for (int n=0;n<4;++n){
      int row = wc*64 + n*16 + (l&15);
      int cp = (l>>4) ^ (row&3);
      bf[n] = *reinterpret_cast<const short8*>(&Bs[row*32 + cp*8]);
    }
    __builtin_amdgcn_s_setprio(1);
    #pragma unroll
    for (int m=0;m<4;++m)
      #pragma unroll
      for (int n=0;n<4;++n)
        acc[m][n] = __builtin_amdgcn_mfma_f32_16x16x32_bf16(af[m], bf[n], acc[m][n], 0,0,0);
    __builtin_amdgcn_s_setprio(0);
  }

  #pragma unroll
  for (int m=0;m<4;++m){
    int row0 = bm*128 + wr*64 + m*16 + ((l>>4)<<2);
    #pragma unroll
    for (int n=0;n<4;++n){
      int col = bn*128 + wc*64 + n*16 + (l&15);
      float bv = BIAS ? bias[col] : 0.0f;
      #pragma unroll
      for (int i=0;i<4;++i){
        float vv = acc[m][n][i] + bv;
        if (RELU) vv = fmaxf(vv, 0.0f);
        size_t off = (size_t)(row0+i)*N + col;
        if (RES) vv += resid[off];
        if (OUTF32) ((float*)outp)[off] = vv;
        else        ((u16*)outp)[off] = f2bf(vv);
      }
    }
  }
}

// ---------------- flash attention v3: swapped QK^T, in-register P ----------------
// grid: BH*(SEQ/QBLK). 4 waves x 32 q-rows (QBLK=128), KBLK=64.
// S^T = mfma(A=K, B=Q): lane holds P[q][k] for q=l&15, k=st*16+(l>>4)*4+i.
// PV uses permuted-k 16x16x32: B = in-register P bf16, A = V^T via 2x ds_read_b64.
#define QBLK 128
#define KBLK 64

__global__ __launch_bounds__(256) void attn_kernel(const u16* __restrict__ qh,
                                                   const u16* __restrict__ ql,
                                                   const u16* __restrict__ kh,
                                                   const u16* __restrict__ kl,
                                                   const u16* __restrict__ vT,
                                                   float* __restrict__ att){
  int id = blockIdx.x;                      // XCD-aware decode
  int bh = (id & 7) + ((id >> 7) << 3);
  int qb = (id >> 3) & 15;
  int t = threadIdx.x, l = t&63, w = t>>6;
  int g = l>>4;

  const size_t hbase = (size_t)bh * SEQ * DH;
  const u16* khb = kh + hbase;
  const u16* klb = kl + hbase;
  const u16* vtb = vT + hbase;              // [64][SEQ]
  int q0 = qb*QBLK + w*32;

  // Q fragments (B-operand): lane l&15 = q, k-chunk (l>>4)*8
  short8 qfh[2][2], qfl[2][2];
  #pragma unroll
  for (int qs=0;qs<2;++qs)
    #pragma unroll
    for (int kc=0;kc<2;++kc){
      size_t off = hbase + (size_t)(q0 + qs*16 + (l&15))*DH + kc*32 + (g<<3);
      qfh[qs][kc] = *reinterpret_cast<const short8*>(qh + off);
      qfl[qs][kc] = *reinterpret_cast<const short8*>(ql + off);
    }

  __shared__ u16 Kh2[2][KBLK*64];
  __shared__ u16 Kl2[2][KBLK*64];
  __shared__ u16 Vt2[2][KBLK*64];

  // O^T accumulators: lane holds q=l&15, d = dt*16 + (l>>4)*4 + i
  f32x4 o[2][4];
  #pragma unroll
  for (int qs=0;qs<2;++qs)
    #pragma unroll
    for (int dt=0;dt<4;++dt)
      #pragma unroll
      for (int i=0;i<4;++i) o[qs][dt][i] = 0.0f;
  float m_run[2] = {-3.0e38f, -3.0e38f};
  float l_run[2] = {0.0f, 0.0f};

  #define STAGE(bb, kt)                                                         \
    { _Pragma("unroll")                                                         \
      for (int i_=0;i_<2;++i_){                                                 \
        int slot = i_*256 + t;                                                  \
        int row = slot>>3, pc = slot&7;                                         \
        int lc = pc ^ swzkey(row);                                              \
        gload_lds16(khb + ((size_t)((kt)*KBLK + row))*DH + lc*8, &Kh2[bb][slot*8]); \
        gload_lds16(klb + ((size_t)((kt)*KBLK + row))*DH + lc*8, &Kl2[bb][slot*8]); \
        gload_lds16(vtb + (size_t)row*SEQ + (kt)*KBLK + lc*8,    &Vt2[bb][slot*8]); \
      } }

  STAGE(0, 0);
  int cur = 0;
  const int NT = SEQ/KBLK;
  for (int kt=0; kt<NT; ++kt){
    __syncthreads();                 // vmcnt(0)+barrier: staged tile ready
    if (kt+1 < NT) STAGE(cur^1, kt+1);

    char* KhB = (char*)&Kh2[cur][0];
    char* KlB = (char*)&Kl2[cur][0];
    char* VtB = (char*)&Vt2[cur][0];

    // ---- S^T = K·Q^T (split, 3 MFMAs per chunk) ----
    f32x4 sc[2][4];
    #pragma unroll
    for (int qs=0;qs<2;++qs)
      #pragma unroll
      for (int st=0;st<4;++st)
        #pragma unroll
        for (int i=0;i<4;++i) sc[qs][st][i] = 0.0f;

    #pragma unroll
    for (int kc=0;kc<2;++kc)
      #pragma unroll
      for (int st=0;st<4;++st){
        int rr = st*16 + (l&15);               // k-row
        int pcK = (kc*4 + g) ^ swzkey(rr);
        short8 kfh = *reinterpret_cast<const short8*>(KhB + rr*128 + pcK*16);
        short8 kfl = *reinterpret_cast<const short8*>(KlB + rr*128 + pcK*16);
        __builtin_amdgcn_s_setprio(1);
        #pragma unroll
        for (int qs=0;qs<2;++qs){
          sc[qs][st] = __builtin_amdgcn_mfma_f32_16x16x32_bf16(kfh, qfh[qs][kc], sc[qs][st], 0,0,0);
          sc[qs][st] = __builtin_amdgcn_mfma_f32_16x16x32_bf16(kfl, qfh[qs][kc], sc[qs][st], 0,0,0);
          sc[qs][st] = __builtin_amdgcn_mfma_f32_16x16x32_bf16(kfh, qfl[qs][kc], sc[qs][st], 0,0,0);
        }
        __builtin_amdgcn_s_setprio(0);
      }

    // ---- per-lane online softmax (row q = l&15; partners l^16, l^32) ----
    short8 pf[2][2];                 // [qs][kc] PV B-fragments
    #pragma unroll
    for (int qs=0;qs<2;++qs){
      float mt = sc[qs][0][0];
      #pragma unroll
      for (int st=0;st<4;++st)
        #pragma unroll
        for (int i=0;i<4;++i) mt = fmaxf(mt, sc[qs][st][i]);
      mt = fmaxf(mt, __shfl_xor(mt, 16));
      mt = fmaxf(mt, __shfl_xor(mt, 32));
      float mn = fmaxf(m_run[qs], mt);
      float scl = __expf(m_run[qs] - mn);
      m_run[qs] = mn;
      float psum = 0.0f;
      u16 pb[16];
      #pragma unroll
      for (int st=0;st<4;++st)
        #pragma unroll
        for (int i=0;i<4;++i){
          float p = __expf(sc[qs][st][i] - mn);
          psum += p;
          pb[st*4+i] = f2bf(p);
        }
      l_run[qs] = l_run[qs]*scl + psum;
      #pragma unroll
      for (int kc=0;kc<2;++kc)
        #pragma unroll
        for (int j=0;j<8;++j) pf[qs][kc][j] = (short)pb[kc*8+j];
      #pragma unroll
      for (int dt=0;dt<4;++dt)
        #pragma unroll
        for (int i=0;i<4;++i) o[qs][dt][i] *= scl;
    }

    // ---- PV: O^T += V^T · P^T (permuted-k fragments) ----
    #pragma unroll
    for (int kc=0;kc<2;++kc)
      #pragma unroll
      for (int dt=0;dt<4;++dt){
        int vr = dt*16 + (l&15);               // d-row
        int sw = swzkey(vr);
        union { uint2 u2[2]; short8 s8; } cv;
        cv.u2[0] = *reinterpret_cast<const uint2*>(VtB + vr*128 + (((kc*4 +     (g>>1)) ^ sw)<<4) + ((g&1)<<3));
        cv.u2[1] = *reinterpret_cast<const uint2*>(VtB + vr*128 + (((kc*4 + 2 + (g>>1)) ^ sw)<<4) + ((g&1)<<3));
        short8 vf = cv.s8;
        __builtin_amdgcn_s_setprio(1);
        o[0][dt] = __builtin_amdgcn_mfma_f32_16x16x32_bf16(vf, pf[0][kc], o[0][dt], 0,0,0);
        o[1][dt] = __builtin_amdgcn_mfma_f32_16x16x32_bf16(vf, pf[1][kc], o[1][dt], 0,0,0);
        __builtin_amdgcn_s_setprio(0);
      }
    cur ^= 1;
  }

  // epilogue: deferred l reduction + store (float4 per dt)
  int b = bh >> 4, hhd = bh & 15;
  #pragma unroll
  for (int qs=0;qs<2;++qs){
    float lt = l_run[qs];
    lt += __shfl_xor(lt, 16);
    lt += __shfl_xor(lt, 32);
    float inv = 1.0f / lt;
    int token = b*SEQ + q0 + qs*16 + (l&15);
    #pragma unroll
    for (int dt=0;dt<4;++dt){
      float4 ov;
      ov.x = o[qs][dt][0]*inv; ov.y = o[qs][dt][1]*inv;
      ov.z = o[qs][dt][2]*inv; ov.w = o[qs][dt][3]*inv;
      *reinterpret_cast<float4*>(att + (size_t)token*DMODEL + hhd*DH + dt*16 + (g<<2)) = ov;
    }
  }
}

// ---------------- launch ----------------
extern "C" void kernel_launch(void* const* d_in, const int* in_sizes, int n_in,
                              void* d_out, int out_size, void* d_ws, size_t ws_size,
                              hipStream_t stream){
  (void)in_sizes; (void)n_in; (void)out_size; (void)ws_size;
  const float* x    = (const float*)d_in[0];
  const float* Wq   = (const float*)d_in[1];
  const float* Wk   = (const float*)d_in[2];
  const float* Wv   = (const float*)d_in[3];
  const float* W1   = (const float*)d_in[4];
  const float* b1   = (const float*)d_in[5];
  const float* W2   = (const float*)d_in[6];
  const float* b2   = (const float*)d_in[7];
  const float* ln1s = (const float*)d_in[8];
  const float* ln1b = (const float*)d_in[9];
  const float* ln2s = (const float*)d_in[10];
  const float* ln2b = (const float*)d_in[11];

  char* ws = (char*)d_ws;
  float* xn_f32  = (float*)ws;  ws += (size_t)NTOK*DMODEL*4;
  float* att_f32 = (float*)ws;  ws += (size_t)NTOK*DMODEL*4;   // first half aliases xnl
  float* xt_f32  = (float*)ws;  ws += (size_t)NTOK*DMODEL*4;
  u16* xt_bf     = (u16*)ws;    ws += (size_t)NTOK*DMODEL*2;   // aliases vrow (dead after vtrans)
  u16* xnh       = (u16*)ws;    ws += (size_t)NTOK*DMODEL*2;
  u16* vT        = (u16*)ws;    ws += (size_t)NTOK*DMODEL*2;
  u16* qh        = (u16*)ws;    ws += (size_t)NTOK*DMODEL*2;   // aliases h_bf (FFN, after attn)
  u16* ql        = (u16*)ws;    ws += (size_t)NTOK*DMODEL*2;
  u16* kh        = (u16*)ws;    ws += (size_t)NTOK*DMODEL*2;
  u16* kl        = (u16*)ws;    ws += (size_t)NTOK*DMODEL*2;
  u16* whi       = (u16*)ws;    ws += (size_t)2*DMODEL*DMODEL*2;
  u16* wlo       = (u16*)ws;    ws += (size_t)2*DMODEL*DMODEL*2;
  u16* wv_bf     = (u16*)ws;    ws += (size_t)DMODEL*DMODEL*2;
  u16* w1_bf     = (u16*)ws;    ws += (size_t)DMODEL*DMODEL*2;
  u16* w2_bf     = (u16*)ws;    ws += (size_t)DMODEL*DMODEL*2;
  u16* xnl       = (u16*)att_f32;   // dead before attn writes att_f32
  u16* vrow      = xt_bf;           // dead before ln2 writes xt_bf
  u16* h_bf      = qh;              // FFN intermediate, after attn

  const int nW = DMODEL*DMODEL;
  const int cvtBlocks = nW/4/256;
  cvt_split<<<cvtBlocks, 256, 0, stream>>>(Wq, whi,      wlo,      nW);
  cvt_split<<<cvtBlocks, 256, 0, stream>>>(Wk, whi + nW, wlo + nW, nW);
  cvt_f32_bf16<<<cvtBlocks, 256, 0, stream>>>(Wv, wv_bf, nW);
  cvt_f32_bf16<<<cvtBlocks, 256, 0, stream>>>(W1, w1_bf, nW);
  cvt_f32_bf16<<<cvtBlocks, 256, 0, stream>>>(W2, w2_bf, nW);

  ln_kernel<<<NTOK, 256, 0, stream>>>(x, nullptr, ln1s, ln1b, xn_f32, xnh, xnl);

  gemm_qk_split<<<dim3(2*DMODEL/128, NTOK/128), 256, 0, stream>>>(
      xnh, xnl, whi, wlo, qh, ql, kh, kl);

  gemm_bt<false,false,false,false><<<dim3(DMODEL/128, NTOK/128), 256, 0, stream>>>(
      xnh, wv_bf, nullptr, nullptr, vrow, NTOK, DMODEL, DMODEL);

  vtrans_kernel<<<BH*(SEQ/64), 256, 0, stream>>>(vrow, vT);

  attn_kernel<<<BH*(SEQ/QBLK), 256, 0, stream>>>(qh, ql, kh, kl, vT, att_f32);

  ln_kernel<<<NTOK, 256, 0, stream>>>(xn_f32, att_f32, ln2s, ln2b, xt_f32, xt_bf, nullptr);

  gemm_bt<true,true,false,false><<<dim3(DMODEL/128, NTOK/128), 256, 0, stream>>>(
      xt_bf, w1_bf, b1, nullptr, h_bf, NTOK, DMODEL, DMODEL);

  gemm_bt<true,false,true,true><<<dim3(DMODEL/128, NTOK/128), 256, 0, stream>>>(
      h_bf, w2_bf, b2, xt_f32, d_out, NTOK, DMODEL, DMODEL);
}